// Round 6
// baseline (272.631 us; speedup 1.0000x reference)
//
#include <hip/hip_runtime.h>
#include <hip/hip_fp16.h>

// GCN 2-layer: out = D_in^-1/2 A D_out^-1/2 (relu(D_in^-1/2 A D_out^-1/2 X W1 + b1)) W2 + b2
// Strategy: project-then-aggregate; CSR-by-dst via DUAL radix partition,
// zero device-scope atomics anywhere.
// R7: radix CSR 368us. R8: dual partition 354us.
// R9 FAILED (1604us): LDS fp32 atomicAdd aggregate -> CAS serialization.
// R10: half-wave/node aggregate, clamped unroll-8: 302us.
// R11 NEUTRAL (303us): MFMA GEMM gain eaten by global-atomic cnt_out
//      (fabric transaction per device atomic on multi-XCD).
// R12: dual partition + MFMA GEMM + batch-16: 284us.
// R13: 16-lane/8B-gather aggregate (batch 12); tot_scan folded into
//      consumers: 267us. part_scatter now top (41us): WRITE_SIZE 91.5MB for
//      8MB payload — 4.9-edge (20B) segments per (bucket,block) dirty a full
//      cacheline each (11x write amplification).
// R14: PA_BLOCKS 416 -> 128: segments 16 edges = 64B (1 line), ~1.5x ampl.
//      row_scan resized to 128-wide rows.

static inline size_t align256(size_t x) { return (x + 255) & ~(size_t)255; }

#define BKT_SHIFT 7
#define BKT_W 128              // nodes per bucket window
#define MAX_NBK 800            // LDS sizing guard (N <= 102400)
#define PA_BLOCKS 128          // partition pass blocks (64B ebuf segments)

typedef _Float16 f16x8 __attribute__((ext_vector_type(8)));
typedef float f32x4 __attribute__((ext_vector_type(4)));

// A1: per-block bucket histograms of BOTH dst>>7 and src>>7.
__global__ __launch_bounds__(256)
void part_hist_kernel(const int* __restrict__ src, const int* __restrict__ dst,
                      int* __restrict__ hist_d, int* __restrict__ hist_s,
                      int nbk, int E, int slice_len) {
    __shared__ int hd[MAX_NBK];
    __shared__ int hs[MAX_NBK];
    const int b = blockIdx.x;
    for (int i = threadIdx.x; i < nbk; i += 256) { hd[i] = 0; hs[i] = 0; }
    __syncthreads();
    const int beg = b * slice_len;
    const int end = min(beg + slice_len, E);
    for (int i = beg + threadIdx.x; i < end; i += 256) {
        atomicAdd(&hd[dst[i] >> BKT_SHIFT], 1);   // LDS atomics (int: native)
        atomicAdd(&hs[src[i] >> BKT_SHIFT], 1);
    }
    __syncthreads();
    for (int i = threadIdx.x; i < nbk; i += 256) {
        hist_d[(size_t)i * PA_BLOCKS + b] = hd[i];
        hist_s[(size_t)i * PA_BLOCKS + b] = hs[i];
    }
}

// A2: per-bucket-row exclusive prefix over the PA_BLOCKS counts (in place),
// row total out (totals stay UN-scanned; consumers scan locally).
// Grid = 2*nbk blocks (dst rows then src rows), 128 threads.
__global__ __launch_bounds__(128)
void row_scan_kernel(int* __restrict__ hist_d, int* __restrict__ hist_s,
                     int* __restrict__ Td, int* __restrict__ Ts, int nbk) {
    __shared__ int tmp[PA_BLOCKS];
    int j = blockIdx.x;
    int* row;
    int* T;
    if (j < nbk) { row = hist_d + (size_t)j * PA_BLOCKS; T = Td; }
    else         { j -= nbk; row = hist_s + (size_t)j * PA_BLOCKS; T = Ts; }
    const int t = threadIdx.x;
    int v = row[t];
    tmp[t] = v;
    __syncthreads();
    for (int off = 1; off < PA_BLOCKS; off <<= 1) {
        int u = (t >= off) ? tmp[t - off] : 0;
        __syncthreads();
        tmp[t] += u;
        __syncthreads();
    }
    row[t] = tmp[t] - v;                          // exclusive within row
    if (t == PA_BLOCKS - 1) T[j] = tmp[t];        // row total
}

// A4: partition scatter. Computes the exclusive scan of the bucket totals
// in LDS (no tot_scan kernel), then scatters.
// ebuf gets (dst&127)<<17 | src (dst-bucketed); sbuf gets 1-byte src&127.
__global__ __launch_bounds__(256)
void part_scatter_kernel(const int* __restrict__ src, const int* __restrict__ dst,
                         const int* __restrict__ hist_d, const int* __restrict__ hist_s,
                         const int* __restrict__ Td, const int* __restrict__ Ts,
                         int* __restrict__ ebuf, unsigned char* __restrict__ sbuf,
                         int nbk, int E, int slice_len) {
    __shared__ int cur_d[MAX_NBK];
    __shared__ int cur_s[MAX_NBK];
    __shared__ int csum[256];
    const int b = blockIdx.x;
    const int t = threadIdx.x;

    // exclusive scan of totals: Td -> cur_d, Ts -> cur_s
#pragma unroll
    for (int p = 0; p < 2; ++p) {
        const int* T = p ? Ts : Td;
        int* curx = p ? cur_s : cur_d;
        const int base = 4 * t;
        int v[4];
        int s = 0;
#pragma unroll
        for (int q = 0; q < 4; ++q) {
            v[q] = (base + q < nbk) ? T[base + q] : 0;
            s += v[q];
        }
        csum[t] = s;
        __syncthreads();
        for (int off = 1; off < 256; off <<= 1) {
            int u = (t >= off) ? csum[t - off] : 0;
            __syncthreads();
            csum[t] += u;
            __syncthreads();
        }
        int run = csum[t] - s;       // exclusive chunk prefix
#pragma unroll
        for (int q = 0; q < 4; ++q) {
            if (base + q < nbk) curx[base + q] = run;
            run += v[q];
        }
        __syncthreads();             // protect csum reuse
    }

    for (int i = t; i < nbk; i += 256) {
        cur_d[i] += hist_d[(size_t)i * PA_BLOCKS + b];
        cur_s[i] += hist_s[(size_t)i * PA_BLOCKS + b];
    }
    __syncthreads();

    const int beg = b * slice_len;
    const int end = min(beg + slice_len, E);
    for (int i = beg + t; i < end; i += 256) {
        int d = dst[i], s = src[i];
        int pd = atomicAdd(&cur_d[d >> BKT_SHIFT], 1);   // LDS atomic
        ebuf[pd] = ((d & (BKT_W - 1)) << 17) | s;
        int ps = atomicAdd(&cur_s[s >> BKT_SHIFT], 1);   // LDS atomic
        sbuf[ps] = (unsigned char)(s & (BKT_W - 1));
    }
}

// B: per-bucket finalize. Computes its bucket base (db/sb) by reducing the
// totals arrays, then emits cnt_in, cnt_out, row_ptr, csr_src.
__global__ __launch_bounds__(256)
void bucket_csr_kernel(const int* __restrict__ ebuf,
                       const unsigned char* __restrict__ sbuf,
                       const int* __restrict__ Td, const int* __restrict__ Ts,
                       int* __restrict__ csr_src,
                       int* __restrict__ cnt_in, int* __restrict__ cnt_out,
                       int* __restrict__ row_ptr,
                       int nbk, int N, int E) {
    __shared__ int cnt[BKT_W];
    __shared__ int rp[BKT_W];
    __shared__ int cur[BKT_W];
    __shared__ int cnts[BKT_W];
    __shared__ int red[256];
    __shared__ int sh_db, sh_sb;
    const int k = blockIdx.x;
    const int lo = k << BKT_SHIFT;
    const int span = min(BKT_W, N - lo);
    const int t = threadIdx.x;

    // db = sum Td[0..k), sb = sum Ts[0..k)
    int s1 = 0, s2 = 0;
    for (int i = t; i < k; i += 256) { s1 += Td[i]; s2 += Ts[i]; }
    red[t] = s1;
    __syncthreads();
    for (int off = 128; off >= 1; off >>= 1) {
        if (t < off) red[t] += red[t + off];
        __syncthreads();
    }
    if (t == 0) sh_db = red[0];
    __syncthreads();
    red[t] = s2;
    __syncthreads();
    for (int off = 128; off >= 1; off >>= 1) {
        if (t < off) red[t] += red[t + off];
        __syncthreads();
    }
    if (t == 0) sh_sb = red[0];
    __syncthreads();
    const int db = sh_db, de = db + Td[k];
    const int sb = sh_sb, se = sb + Ts[k];

    if (t < BKT_W) { cnt[t] = 0; cnts[t] = 0; }
    __syncthreads();
    for (int i = db + t; i < de; i += 256) atomicAdd(&cnt[ebuf[i] >> 17], 1);
    for (int i = sb + t; i < se; i += 256) atomicAdd(&cnts[sbuf[i]], 1);
    __syncthreads();
    if (t < BKT_W) rp[t] = cnt[t];
    __syncthreads();
    for (int off = 1; off < BKT_W; off <<= 1) {
        int v = (t < BKT_W && t >= off) ? rp[t - off] : 0;
        __syncthreads();
        if (t < BKT_W) rp[t] += v;
        __syncthreads();
    }
    if (t < span) {
        row_ptr[lo + t] = db + rp[t] - cnt[t];
        cnt_in[lo + t]  = cnt[t];
        cnt_out[lo + t] = cnts[t];
    }
    __syncthreads();
    if (t < BKT_W) cur[t] = db + rp[t] - cnt[t];
    __syncthreads();
    for (int i = db + t; i < de; i += 256) {
        int p = ebuf[i];
        int pos = atomicAdd(&cur[p >> 17], 1);           // LDS atomic
        csr_src[pos] = p & 0x1FFFF;
    }
    if (k == 0 && t == 0) row_ptr[N] = E;
}

// MFMA GEMM: Y[n][j] = (sum_k X[n][k] * W[k][j]) * rsqrt(max(cnt_out[n],1)),
// stored fp16. hi/lo fp16 split: X=Xh+Xl, W=Wh+Wl (each to 2^-22 rel);
// D = Xh*Wh + Xh*Wl + Xl*Wh via mfma_f32_16x16x32_f16, fp32 accumulate.
template <int K>
__global__ __launch_bounds__(256)
void gemm_scale_kernel(const float* __restrict__ X, const float* __restrict__ W,
                       const int* __restrict__ cnt_out,
                       __half* __restrict__ Y, int N) {
    __shared__ _Float16 Wt[2][64][K + 8];   // [hi/lo][col][k]
    const int t = threadIdx.x;
    for (int i = t; i < K * 64; i += 256) {
        const int k = i >> 6, j = i & 63;
        const float w = W[i];
        const _Float16 hi = (_Float16)w;
        Wt[0][j][k] = hi;
        Wt[1][j][k] = (_Float16)(w - (float)hi);
    }
    __syncthreads();

    const int wid  = t >> 6;
    const int lane = t & 63;
    const int col  = lane & 15;
    const int kg   = (lane >> 4) * 8;        // lane's k-offset within a 32-chunk

    const int rowA = blockIdx.x * 64 + wid * 16 + col;   // A-frag row
    const size_t xbase = (size_t)min(rowA, N - 1) * K;

    f32x4 acc0 = {}, acc1 = {}, acc2 = {}, acc3 = {};

#pragma unroll
    for (int ks = 0; ks < K; ks += 32) {
        float4 xa = *(const float4*)&X[xbase + ks + kg];
        float4 xb = *(const float4*)&X[xbase + ks + kg + 4];
        const float xs[8] = {xa.x, xa.y, xa.z, xa.w, xb.x, xb.y, xb.z, xb.w};
        f16x8 ahi, alo;
#pragma unroll
        for (int j = 0; j < 8; ++j) {
            const _Float16 h = (_Float16)xs[j];
            ahi[j] = h;
            alo[j] = (_Float16)(xs[j] - (float)h);
        }
#pragma unroll
        for (int tile = 0; tile < 4; ++tile) {
            const f16x8 bhi = *(const f16x8*)&Wt[0][col + 16 * tile][ks + kg];
            const f16x8 blo = *(const f16x8*)&Wt[1][col + 16 * tile][ks + kg];
            f32x4* acc = (tile == 0) ? &acc0 : (tile == 1) ? &acc1
                       : (tile == 2) ? &acc2 : &acc3;
            *acc = __builtin_amdgcn_mfma_f32_16x16x32_f16(ahi, bhi, *acc, 0, 0, 0);
            *acc = __builtin_amdgcn_mfma_f32_16x16x32_f16(alo, bhi, *acc, 0, 0, 0);
            *acc = __builtin_amdgcn_mfma_f32_16x16x32_f16(ahi, blo, *acc, 0, 0, 0);
        }
    }

    // D layout: col = lane&15, row = (lane>>4)*4 + reg   [m89-verified]
    const int rbase = blockIdx.x * 64 + wid * 16 + (lane >> 4) * 4;
#pragma unroll
    for (int r = 0; r < 4; ++r) {
        const int rr = rbase + r;
        if (rr < N) {
            const float sc = rsqrtf((float)max(cnt_out[rr], 1));
            __half* yp = &Y[(size_t)rr * 64 + col];
            yp[0]  = __float2half_rn(acc0[r] * sc);
            yp[16] = __float2half_rn(acc1[r] * sc);
            yp[32] = __float2half_rn(acc2[r] * sc);
            yp[48] = __float2half_rn(acc3[r] * sc);
        }
    }
}

// out[n][f] = (sum_{in-edges} Y[src][f]) * rsqrt(max(cnt_in[n],1)) + bias[f]
// 16 lanes per node (4 nodes/wave); lane = 2 half2 feature pairs (8B gather).
// Clamped batch-12 edge loop: EVERY row runs with 12 gathers in flight
// (clamp-duplicates hit the same cacheline ~ free). No atomics, no shuffles.
template <bool RELU>
__global__ __launch_bounds__(256)
void aggregate_kernel(const __half* __restrict__ Y,
                      const int* __restrict__ row_ptr,
                      const int* __restrict__ csr_src,
                      const int* __restrict__ cnt_in,
                      const float* __restrict__ bias,
                      float* __restrict__ out, int N) {
    const int n = blockIdx.x * 16 + (threadIdx.x >> 4);
    if (n >= N) return;
    const int fq = threadIdx.x & 15;          // features 4*fq .. 4*fq+3

    const int start = row_ptr[n];
    const int end   = row_ptr[n + 1];
    const int last  = end - 1;

    float4 acc = {0.f, 0.f, 0.f, 0.f};
    for (int e = start; e < end; e += 12) {
        int idx[12];
#pragma unroll
        for (int j = 0; j < 12; ++j) idx[j] = csr_src[min(e + j, last)];
        uint2 v[12];
#pragma unroll
        for (int j = 0; j < 12; ++j)
            v[j] = *((const uint2*)(Y + ((size_t)idx[j] << 6)) + fq);
#pragma unroll
        for (int j = 0; j < 12; ++j) {
            if (e + j < end) {
                float2 a = __half22float2(*(const __half2*)&v[j].x);
                float2 b = __half22float2(*(const __half2*)&v[j].y);
                acc.x += a.x; acc.y += a.y; acc.z += b.x; acc.w += b.y;
            }
        }
    }

    const float sc = rsqrtf((float)max(cnt_in[n], 1));
    const float4 bb = *(const float4*)&bias[4 * fq];
    float4 o;
    o.x = acc.x * sc + bb.x;
    o.y = acc.y * sc + bb.y;
    o.z = acc.z * sc + bb.z;
    o.w = acc.w * sc + bb.w;
    if (RELU) {
        o.x = fmaxf(o.x, 0.f); o.y = fmaxf(o.y, 0.f);
        o.z = fmaxf(o.z, 0.f); o.w = fmaxf(o.w, 0.f);
    }
    *(float4*)&out[((size_t)n << 6) + 4 * fq] = o;
}

extern "C" void kernel_launch(void* const* d_in, const int* in_sizes, int n_in,
                              void* d_out, int out_size, void* d_ws, size_t ws_size,
                              hipStream_t stream) {
    const float* x   = (const float*)d_in[0];
    const int*   src = (const int*)d_in[1];
    const int*   dst = (const int*)d_in[2];
    const float* W1  = (const float*)d_in[3];
    const float* b1  = (const float*)d_in[4];
    const float* W2  = (const float*)d_in[5];
    const float* b2  = (const float*)d_in[6];
    float* out = (float*)d_out;

    const int N = in_sizes[0] / 128;   // 100000
    const int E = in_sizes[1];         // 1600000

    const int nbk = (N + BKT_W - 1) >> BKT_SHIFT;          // 782 buckets
    const int M = nbk * PA_BLOCKS;

    // Workspace (~25 MB). d_out doubles as the hidden-layer buffer.
    char* ws = (char*)d_ws;
    size_t off = 0;
    __half* Y       = (__half*)(ws + off); off = align256(off + (size_t)N * 64 * sizeof(__half));
    int* csr_src    = (int*)(ws + off);    off = align256(off + (size_t)E * sizeof(int));
    int* ebuf       = (int*)(ws + off);    off = align256(off + (size_t)E * sizeof(int));
    unsigned char* sbuf = (unsigned char*)(ws + off); off = align256(off + (size_t)E);
    int* hist_d     = (int*)(ws + off);    off = align256(off + (size_t)M * sizeof(int));
    int* hist_s     = (int*)(ws + off);    off = align256(off + (size_t)M * sizeof(int));
    int* Td         = (int*)(ws + off);    off = align256(off + (size_t)nbk * sizeof(int));
    int* Ts         = (int*)(ws + off);    off = align256(off + (size_t)nbk * sizeof(int));
    int* cnt_out    = (int*)(ws + off);    off = align256(off + (size_t)N * sizeof(int));
    int* cnt_in     = (int*)(ws + off);    off = align256(off + (size_t)N * sizeof(int));
    int* row_ptr    = (int*)(ws + off);    off = align256(off + (size_t)(N + 1) * sizeof(int));

    const int pslice = (E + PA_BLOCKS - 1) / PA_BLOCKS;

    // Dual radix-partition CSR build + degree counts (zero device atomics)
    part_hist_kernel<<<PA_BLOCKS, 256, 0, stream>>>(src, dst, hist_d, hist_s, nbk, E, pslice);
    row_scan_kernel<<<2 * nbk, 128, 0, stream>>>(hist_d, hist_s, Td, Ts, nbk);
    part_scatter_kernel<<<PA_BLOCKS, 256, 0, stream>>>(src, dst, hist_d, hist_s, Td, Ts,
                                                       ebuf, sbuf, nbk, E, pslice);
    bucket_csr_kernel<<<nbk, 256, 0, stream>>>(ebuf, sbuf, Td, Ts, csr_src,
                                               cnt_in, cnt_out, row_ptr, nbk, N, E);

    const int gemm_blocks = (N + 63) / 64;
    const int agg_blocks  = (N + 15) / 16;

    // Layer 1: Y = fp16[(X @ W1) * rs_out] ; agg -> d_out (hidden, relu)
    gemm_scale_kernel<128><<<gemm_blocks, 256, 0, stream>>>(x, W1, cnt_out, Y, N);
    aggregate_kernel<true><<<agg_blocks, 256, 0, stream>>>(Y, row_ptr, csr_src, cnt_in, b1, out, N);

    // Layer 2: Y = fp16[(H @ W2) * rs_out] ; agg -> d_out (final)
    gemm_scale_kernel<64><<<gemm_blocks, 256, 0, stream>>>(out, W2, cnt_out, Y, N);
    aggregate_kernel<false><<<agg_blocks, 256, 0, stream>>>(Y, row_ptr, csr_src, cnt_in, b2, out, N);
}

// Round 7
// 249.386 us; speedup vs baseline: 1.0932x; 1.0932x over previous
//
#include <hip/hip_runtime.h>
#include <hip/hip_fp16.h>

// GCN 2-layer: out = D_in^-1/2 A D_out^-1/2 (relu(D_in^-1/2 A D_out^-1/2 X W1 + b1)) W2 + b2
// Strategy: project-then-aggregate; bucket-partitioned edges, single-pass
// scatter into fixed-capacity bucket regions, per-bucket CSR finalize.
// R8 dual partition 354us. R9 FAILED: LDS fp32 atomics (CAS serialization).
// R10 clamped-unroll aggregate 302us. R11 NEUTRAL: MFMA GEMM gain eaten by
//     1.6M global atomics (fabric transaction each on multi-XCD).
// R12 284us. R13 267us (16-lane/8B aggregate; tot_scan folded).
// R14 REGRESSED (272.6us): PA_BLOCKS=128 starved CUs — part_hist 45.6us at
//     occupancy 4.7%. Bound = LDS-atomic throughput x active CUs, not HBM.
// R15: single-pass partition. 256 blocks x 512 thr (all CUs); per-block LDS
//     hist -> ~200K device atomics reserve space in fixed-cap bucket regions
//     (CAP=5120, mean 4092, 16-sigma headroom) -> LDS-cursor scatter (2nd
//     slice read L2-hot). Deletes part_hist + row_scan. Buckets widened to
//     256 nodes (391 buckets): 64B segments AND full parallelism.

static inline size_t align256(size_t x) { return (x + 255) & ~(size_t)255; }

#define BKT_SHIFT 8
#define BKT_W 256              // nodes per bucket window
#define MAX_NBK 400            // LDS sizing guard (N <= 102400)
#define CAP 5120               // per-bucket region capacity (mean 4092, +16s)
#define SC_BLOCKS 256          // scatter blocks (1 per CU)
#define SC_THREADS 512

typedef _Float16 f16x8 __attribute__((ext_vector_type(8)));
typedef float f32x4 __attribute__((ext_vector_type(4)));

// A: single-pass partition. Per block: LDS hist of slice -> device-atomic
// region reservation (one per touched bucket) -> LDS-cursor scatter.
// ebuf gets (dst&255)<<17 | src in dst-bucket region; sbuf gets 1-byte
// src&255 in src-bucket region (for cnt_out).
__global__ __launch_bounds__(SC_THREADS)
void scatter_atomic_kernel(const int* __restrict__ src, const int* __restrict__ dst,
                           int* __restrict__ gcnt_d, int* __restrict__ gcnt_s,
                           int* __restrict__ ebuf, unsigned char* __restrict__ sbuf,
                           int nbk, int E, int slice_len) {
    __shared__ int hd[MAX_NBK];
    __shared__ int hs[MAX_NBK];
    __shared__ int cur_d[MAX_NBK];
    __shared__ int cur_s[MAX_NBK];
    const int b = blockIdx.x;
    const int t = threadIdx.x;
    for (int i = t; i < nbk; i += SC_THREADS) { hd[i] = 0; hs[i] = 0; }
    __syncthreads();
    const int beg = b * slice_len;
    const int end = min(beg + slice_len, E);
    for (int i = beg + t; i < end; i += SC_THREADS) {
        atomicAdd(&hd[dst[i] >> BKT_SHIFT], 1);   // LDS atomic (int: native)
        atomicAdd(&hs[src[i] >> BKT_SHIFT], 1);
    }
    __syncthreads();
    // reserve: ~2*nbk device atomics per block (~200K total, not per-edge)
    for (int i = t; i < nbk; i += SC_THREADS) {
        int c = hd[i];
        cur_d[i] = i * CAP + (c ? atomicAdd(&gcnt_d[i], c) : 0);
        c = hs[i];
        cur_s[i] = i * CAP + (c ? atomicAdd(&gcnt_s[i], c) : 0);
    }
    __syncthreads();
    for (int i = beg + t; i < end; i += SC_THREADS) {  // slice is L2-hot now
        int d = dst[i], s = src[i];
        int pd = atomicAdd(&cur_d[d >> BKT_SHIFT], 1);   // LDS atomic
        ebuf[pd] = ((d & (BKT_W - 1)) << 17) | s;
        int ps = atomicAdd(&cur_s[s >> BKT_SHIFT], 1);   // LDS atomic
        sbuf[ps] = (unsigned char)(s & (BKT_W - 1));
    }
}

// B: per-bucket finalize. db = prefix over gcnt_d (block reduction); emits
// cnt_in, cnt_out, row_ptr, csr_src (contiguous CSR, bucket-local writes).
__global__ __launch_bounds__(256)
void bucket_csr_kernel(const int* __restrict__ ebuf,
                       const unsigned char* __restrict__ sbuf,
                       const int* __restrict__ gcnt_d, const int* __restrict__ gcnt_s,
                       int* __restrict__ csr_src,
                       int* __restrict__ cnt_in, int* __restrict__ cnt_out,
                       int* __restrict__ row_ptr,
                       int nbk, int N, int E) {
    __shared__ int cnt[BKT_W];
    __shared__ int rp[BKT_W];
    __shared__ int cur[BKT_W];
    __shared__ int cnts[BKT_W];
    __shared__ int red[256];
    __shared__ int sh_db;
    const int k = blockIdx.x;
    const int lo = k << BKT_SHIFT;
    const int span = min(BKT_W, N - lo);
    const int t = threadIdx.x;

    // db = sum gcnt_d[0..k)
    int s1 = 0;
    for (int i = t; i < k; i += 256) s1 += gcnt_d[i];
    red[t] = s1;
    __syncthreads();
    for (int off = 128; off >= 1; off >>= 1) {
        if (t < off) red[t] += red[t + off];
        __syncthreads();
    }
    if (t == 0) sh_db = red[0];
    __syncthreads();
    const int db = sh_db;
    const int eb = k * CAP, ee = eb + gcnt_d[k];
    const int sb = k * CAP, se = sb + gcnt_s[k];

    cnt[t] = 0; cnts[t] = 0;
    __syncthreads();
    for (int i = eb + t; i < ee; i += 256) atomicAdd(&cnt[ebuf[i] >> 17], 1);
    for (int i = sb + t; i < se; i += 256) atomicAdd(&cnts[sbuf[i]], 1);
    __syncthreads();
    rp[t] = cnt[t];
    __syncthreads();
    for (int off = 1; off < BKT_W; off <<= 1) {
        int v = (t >= off) ? rp[t - off] : 0;
        __syncthreads();
        rp[t] += v;
        __syncthreads();
    }
    if (t < span) {
        row_ptr[lo + t] = db + rp[t] - cnt[t];
        cnt_in[lo + t]  = cnt[t];
        cnt_out[lo + t] = cnts[t];
    }
    __syncthreads();
    cur[t] = db + rp[t] - cnt[t];
    __syncthreads();
    for (int i = eb + t; i < ee; i += 256) {
        int p = ebuf[i];
        int pos = atomicAdd(&cur[p >> 17], 1);           // LDS atomic
        csr_src[pos] = p & 0x1FFFF;
    }
    if (k == 0 && t == 0) row_ptr[N] = E;
}

// MFMA GEMM: Y[n][j] = (sum_k X[n][k] * W[k][j]) * rsqrt(max(cnt_out[n],1)),
// stored fp16. hi/lo fp16 split: X=Xh+Xl, W=Wh+Wl (each to 2^-22 rel);
// D = Xh*Wh + Xh*Wl + Xl*Wh via mfma_f32_16x16x32_f16, fp32 accumulate.
template <int K>
__global__ __launch_bounds__(256)
void gemm_scale_kernel(const float* __restrict__ X, const float* __restrict__ W,
                       const int* __restrict__ cnt_out,
                       __half* __restrict__ Y, int N) {
    __shared__ _Float16 Wt[2][64][K + 8];   // [hi/lo][col][k]
    const int t = threadIdx.x;
    for (int i = t; i < K * 64; i += 256) {
        const int k = i >> 6, j = i & 63;
        const float w = W[i];
        const _Float16 hi = (_Float16)w;
        Wt[0][j][k] = hi;
        Wt[1][j][k] = (_Float16)(w - (float)hi);
    }
    __syncthreads();

    const int wid  = t >> 6;
    const int lane = t & 63;
    const int col  = lane & 15;
    const int kg   = (lane >> 4) * 8;        // lane's k-offset within a 32-chunk

    const int rowA = blockIdx.x * 64 + wid * 16 + col;   // A-frag row
    const size_t xbase = (size_t)min(rowA, N - 1) * K;

    f32x4 acc0 = {}, acc1 = {}, acc2 = {}, acc3 = {};

#pragma unroll
    for (int ks = 0; ks < K; ks += 32) {
        float4 xa = *(const float4*)&X[xbase + ks + kg];
        float4 xb = *(const float4*)&X[xbase + ks + kg + 4];
        const float xs[8] = {xa.x, xa.y, xa.z, xa.w, xb.x, xb.y, xb.z, xb.w};
        f16x8 ahi, alo;
#pragma unroll
        for (int j = 0; j < 8; ++j) {
            const _Float16 h = (_Float16)xs[j];
            ahi[j] = h;
            alo[j] = (_Float16)(xs[j] - (float)h);
        }
#pragma unroll
        for (int tile = 0; tile < 4; ++tile) {
            const f16x8 bhi = *(const f16x8*)&Wt[0][col + 16 * tile][ks + kg];
            const f16x8 blo = *(const f16x8*)&Wt[1][col + 16 * tile][ks + kg];
            f32x4* acc = (tile == 0) ? &acc0 : (tile == 1) ? &acc1
                       : (tile == 2) ? &acc2 : &acc3;
            *acc = __builtin_amdgcn_mfma_f32_16x16x32_f16(ahi, bhi, *acc, 0, 0, 0);
            *acc = __builtin_amdgcn_mfma_f32_16x16x32_f16(alo, bhi, *acc, 0, 0, 0);
            *acc = __builtin_amdgcn_mfma_f32_16x16x32_f16(ahi, blo, *acc, 0, 0, 0);
        }
    }

    // D layout: col = lane&15, row = (lane>>4)*4 + reg   [m89-verified]
    const int rbase = blockIdx.x * 64 + wid * 16 + (lane >> 4) * 4;
#pragma unroll
    for (int r = 0; r < 4; ++r) {
        const int rr = rbase + r;
        if (rr < N) {
            const float sc = rsqrtf((float)max(cnt_out[rr], 1));
            __half* yp = &Y[(size_t)rr * 64 + col];
            yp[0]  = __float2half_rn(acc0[r] * sc);
            yp[16] = __float2half_rn(acc1[r] * sc);
            yp[32] = __float2half_rn(acc2[r] * sc);
            yp[48] = __float2half_rn(acc3[r] * sc);
        }
    }
}

// out[n][f] = (sum_{in-edges} Y[src][f]) * rsqrt(max(cnt_in[n],1)) + bias[f]
// 16 lanes per node (4 nodes/wave); lane = 2 half2 feature pairs (8B gather).
// Clamped batch-12 edge loop: EVERY row runs with 12 gathers in flight
// (clamp-duplicates hit the same cacheline ~ free). No atomics, no shuffles.
template <bool RELU>
__global__ __launch_bounds__(256)
void aggregate_kernel(const __half* __restrict__ Y,
                      const int* __restrict__ row_ptr,
                      const int* __restrict__ csr_src,
                      const int* __restrict__ cnt_in,
                      const float* __restrict__ bias,
                      float* __restrict__ out, int N) {
    const int n = blockIdx.x * 16 + (threadIdx.x >> 4);
    if (n >= N) return;
    const int fq = threadIdx.x & 15;          // features 4*fq .. 4*fq+3

    const int start = row_ptr[n];
    const int end   = row_ptr[n + 1];
    const int last  = end - 1;

    float4 acc = {0.f, 0.f, 0.f, 0.f};
    for (int e = start; e < end; e += 12) {
        int idx[12];
#pragma unroll
        for (int j = 0; j < 12; ++j) idx[j] = csr_src[min(e + j, last)];
        uint2 v[12];
#pragma unroll
        for (int j = 0; j < 12; ++j)
            v[j] = *((const uint2*)(Y + ((size_t)idx[j] << 6)) + fq);
#pragma unroll
        for (int j = 0; j < 12; ++j) {
            if (e + j < end) {
                float2 a = __half22float2(*(const __half2*)&v[j].x);
                float2 b = __half22float2(*(const __half2*)&v[j].y);
                acc.x += a.x; acc.y += a.y; acc.z += b.x; acc.w += b.y;
            }
        }
    }

    const float sc = rsqrtf((float)max(cnt_in[n], 1));
    const float4 bb = *(const float4*)&bias[4 * fq];
    float4 o;
    o.x = acc.x * sc + bb.x;
    o.y = acc.y * sc + bb.y;
    o.z = acc.z * sc + bb.z;
    o.w = acc.w * sc + bb.w;
    if (RELU) {
        o.x = fmaxf(o.x, 0.f); o.y = fmaxf(o.y, 0.f);
        o.z = fmaxf(o.z, 0.f); o.w = fmaxf(o.w, 0.f);
    }
    *(float4*)&out[((size_t)n << 6) + 4 * fq] = o;
}

extern "C" void kernel_launch(void* const* d_in, const int* in_sizes, int n_in,
                              void* d_out, int out_size, void* d_ws, size_t ws_size,
                              hipStream_t stream) {
    const float* x   = (const float*)d_in[0];
    const int*   src = (const int*)d_in[1];
    const int*   dst = (const int*)d_in[2];
    const float* W1  = (const float*)d_in[3];
    const float* b1  = (const float*)d_in[4];
    const float* W2  = (const float*)d_in[5];
    const float* b2  = (const float*)d_in[6];
    float* out = (float*)d_out;

    const int N = in_sizes[0] / 128;   // 100000
    const int E = in_sizes[1];         // 1600000

    const int nbk = (N + BKT_W - 1) >> BKT_SHIFT;          // 391 buckets

    // Workspace (~31 MB). d_out doubles as the hidden-layer buffer.
    char* ws = (char*)d_ws;
    size_t off = 0;
    __half* Y       = (__half*)(ws + off); off = align256(off + (size_t)N * 64 * sizeof(__half));
    int* csr_src    = (int*)(ws + off);    off = align256(off + (size_t)E * sizeof(int));
    int* ebuf       = (int*)(ws + off);    off = align256(off + (size_t)nbk * CAP * sizeof(int));
    unsigned char* sbuf = (unsigned char*)(ws + off); off = align256(off + (size_t)nbk * CAP);
    int* gcnt_d     = (int*)(ws + off);    off = align256(off + (size_t)nbk * sizeof(int));
    int* gcnt_s     = (int*)(ws + off);    off = align256(off + (size_t)nbk * sizeof(int));
    int* cnt_out    = (int*)(ws + off);    off = align256(off + (size_t)N * sizeof(int));
    int* cnt_in     = (int*)(ws + off);    off = align256(off + (size_t)N * sizeof(int));
    int* row_ptr    = (int*)(ws + off);    off = align256(off + (size_t)(N + 1) * sizeof(int));

    const int pslice = (E + SC_BLOCKS - 1) / SC_BLOCKS;

    // Single-pass bucket partition (region counters zeroed first)
    hipMemsetAsync(gcnt_d, 0, (size_t)nbk * sizeof(int), stream);
    hipMemsetAsync(gcnt_s, 0, (size_t)nbk * sizeof(int), stream);
    scatter_atomic_kernel<<<SC_BLOCKS, SC_THREADS, 0, stream>>>(
        src, dst, gcnt_d, gcnt_s, ebuf, sbuf, nbk, E, pslice);
    bucket_csr_kernel<<<nbk, 256, 0, stream>>>(ebuf, sbuf, gcnt_d, gcnt_s, csr_src,
                                               cnt_in, cnt_out, row_ptr, nbk, N, E);

    const int gemm_blocks = (N + 63) / 64;
    const int agg_blocks  = (N + 15) / 16;

    // Layer 1: Y = fp16[(X @ W1) * rs_out] ; agg -> d_out (hidden, relu)
    gemm_scale_kernel<128><<<gemm_blocks, 256, 0, stream>>>(x, W1, cnt_out, Y, N);
    aggregate_kernel<true><<<agg_blocks, 256, 0, stream>>>(Y, row_ptr, csr_src, cnt_in, b1, out, N);

    // Layer 2: Y = fp16[(H @ W2) * rs_out] ; agg -> d_out (final)
    gemm_scale_kernel<64><<<gemm_blocks, 256, 0, stream>>>(out, W2, cnt_out, Y, N);
    aggregate_kernel<false><<<agg_blocks, 256, 0, stream>>>(Y, row_ptr, csr_src, cnt_in, b2, out, N);
}

// Round 9
// 245.443 us; speedup vs baseline: 1.1108x; 1.0161x over previous
//
#include <hip/hip_runtime.h>
#include <hip/hip_fp16.h>

// GCN 2-layer: out = D_in^-1/2 A D_out^-1/2 (relu(D_in^-1/2 A D_out^-1/2 X W1 + b1)) W2 + b2
// Strategy: project-then-aggregate; bucket-partitioned edges, single-pass
// scatter into fixed-capacity bucket regions, per-bucket CSR finalize,
// fused aggregate+GEMM for layer 2.
// R8 354us. R9 FAILED: LDS fp32 atomics (CAS serialization).
// R10 302us. R11 NEUTRAL: MFMA GEMM gain eaten by 1.6M device atomics
//     (fabric transaction each; 200K is fine — R15).
// R12 284us. R13 267us. R14 REGRESSED 272.6us (CU starvation at 128 blocks).
// R15 249us: single-pass partition (per-block LDS hist -> ~200K device-atomic
//     region reservations, CAP=5120 -> LDS-cursor scatter, 2nd read L2-hot).
//     All own kernels now < 41us fill noise; ~70us residual is launch/gap
//     overhead of the 8-dispatch serial chain.
// R16: (a) fuse layer-2 GEMM into layer-1 aggregate (hidden never touches
//     HBM: -51MB traffic, -1 dispatch). Phase 1 = batch-12 aggregate ->
//     hidden hi/lo fp16 in LDS; phase 2 = 16x64 @ 64x64 MFMA (verified tile
//     layout reused), scaled by rs_out -> Y2 fp16.
//     (b) single contiguous memset for both gcnt tables. 8 -> 6 dispatches.
// R17: R16 resubmit (container infra failure, no data; audit found no
//     barrier-divergence/OOB/hang candidates).

static inline size_t align256(size_t x) { return (x + 255) & ~(size_t)255; }

#define BKT_SHIFT 8
#define BKT_W 256              // nodes per bucket window
#define MAX_NBK 400            // LDS sizing guard (N <= 102400)
#define CAP 5120               // per-bucket region capacity (mean 4092, +16s)
#define SC_BLOCKS 256          // scatter blocks (1 per CU)
#define SC_THREADS 512

typedef _Float16 f16x8 __attribute__((ext_vector_type(8)));
typedef float f32x4 __attribute__((ext_vector_type(4)));

// A: single-pass partition. Per block: LDS hist of slice -> device-atomic
// region reservation (one per touched bucket) -> LDS-cursor scatter.
__global__ __launch_bounds__(SC_THREADS)
void scatter_atomic_kernel(const int* __restrict__ src, const int* __restrict__ dst,
                           int* __restrict__ gcnt_d, int* __restrict__ gcnt_s,
                           int* __restrict__ ebuf, unsigned char* __restrict__ sbuf,
                           int nbk, int E, int slice_len) {
    __shared__ int hd[MAX_NBK];
    __shared__ int hs[MAX_NBK];
    __shared__ int cur_d[MAX_NBK];
    __shared__ int cur_s[MAX_NBK];
    const int b = blockIdx.x;
    const int t = threadIdx.x;
    for (int i = t; i < nbk; i += SC_THREADS) { hd[i] = 0; hs[i] = 0; }
    __syncthreads();
    const int beg = b * slice_len;
    const int end = min(beg + slice_len, E);
    for (int i = beg + t; i < end; i += SC_THREADS) {
        atomicAdd(&hd[dst[i] >> BKT_SHIFT], 1);   // LDS atomic (int: native)
        atomicAdd(&hs[src[i] >> BKT_SHIFT], 1);
    }
    __syncthreads();
    // reserve: ~2*nbk device atomics per block (~200K total, not per-edge)
    for (int i = t; i < nbk; i += SC_THREADS) {
        int c = hd[i];
        cur_d[i] = i * CAP + (c ? atomicAdd(&gcnt_d[i], c) : 0);
        c = hs[i];
        cur_s[i] = i * CAP + (c ? atomicAdd(&gcnt_s[i], c) : 0);
    }
    __syncthreads();
    for (int i = beg + t; i < end; i += SC_THREADS) {  // slice is L2-hot now
        int d = dst[i], s = src[i];
        int pd = atomicAdd(&cur_d[d >> BKT_SHIFT], 1);   // LDS atomic
        ebuf[pd] = ((d & (BKT_W - 1)) << 17) | s;
        int ps = atomicAdd(&cur_s[s >> BKT_SHIFT], 1);   // LDS atomic
        sbuf[ps] = (unsigned char)(s & (BKT_W - 1));
    }
}

// B: per-bucket finalize. db = prefix over gcnt_d (block reduction); emits
// cnt_in, cnt_out, row_ptr, csr_src (contiguous CSR, bucket-local writes).
__global__ __launch_bounds__(256)
void bucket_csr_kernel(const int* __restrict__ ebuf,
                       const unsigned char* __restrict__ sbuf,
                       const int* __restrict__ gcnt_d, const int* __restrict__ gcnt_s,
                       int* __restrict__ csr_src,
                       int* __restrict__ cnt_in, int* __restrict__ cnt_out,
                       int* __restrict__ row_ptr,
                       int nbk, int N, int E) {
    __shared__ int cnt[BKT_W];
    __shared__ int rp[BKT_W];
    __shared__ int cur[BKT_W];
    __shared__ int cnts[BKT_W];
    __shared__ int red[256];
    __shared__ int sh_db;
    const int k = blockIdx.x;
    const int lo = k << BKT_SHIFT;
    const int span = min(BKT_W, N - lo);
    const int t = threadIdx.x;

    // db = sum gcnt_d[0..k)
    int s1 = 0;
    for (int i = t; i < k; i += 256) s1 += gcnt_d[i];
    red[t] = s1;
    __syncthreads();
    for (int off = 128; off >= 1; off >>= 1) {
        if (t < off) red[t] += red[t + off];
        __syncthreads();
    }
    if (t == 0) sh_db = red[0];
    __syncthreads();
    const int db = sh_db;
    const int eb = k * CAP, ee = eb + gcnt_d[k];
    const int sb = k * CAP, se = sb + gcnt_s[k];

    cnt[t] = 0; cnts[t] = 0;
    __syncthreads();
    for (int i = eb + t; i < ee; i += 256) atomicAdd(&cnt[ebuf[i] >> 17], 1);
    for (int i = sb + t; i < se; i += 256) atomicAdd(&cnts[sbuf[i]], 1);
    __syncthreads();
    rp[t] = cnt[t];
    __syncthreads();
    for (int off = 1; off < BKT_W; off <<= 1) {
        int v = (t >= off) ? rp[t - off] : 0;
        __syncthreads();
        rp[t] += v;
        __syncthreads();
    }
    if (t < span) {
        row_ptr[lo + t] = db + rp[t] - cnt[t];
        cnt_in[lo + t]  = cnt[t];
        cnt_out[lo + t] = cnts[t];
    }
    __syncthreads();
    cur[t] = db + rp[t] - cnt[t];
    __syncthreads();
    for (int i = eb + t; i < ee; i += 256) {
        int p = ebuf[i];
        int pos = atomicAdd(&cur[p >> 17], 1);           // LDS atomic
        csr_src[pos] = p & 0x1FFFF;
    }
    if (k == 0 && t == 0) row_ptr[N] = E;
}

// MFMA GEMM: Y[n][j] = (sum_k X[n][k] * W[k][j]) * rsqrt(max(cnt_out[n],1)),
// stored fp16. hi/lo fp16 split (error ~2^-22), fp32 accumulate.
template <int K>
__global__ __launch_bounds__(256)
void gemm_scale_kernel(const float* __restrict__ X, const float* __restrict__ W,
                       const int* __restrict__ cnt_out,
                       __half* __restrict__ Y, int N) {
    __shared__ _Float16 Wt[2][64][K + 8];   // [hi/lo][col][k]
    const int t = threadIdx.x;
    for (int i = t; i < K * 64; i += 256) {
        const int k = i >> 6, j = i & 63;
        const float w = W[i];
        const _Float16 hi = (_Float16)w;
        Wt[0][j][k] = hi;
        Wt[1][j][k] = (_Float16)(w - (float)hi);
    }
    __syncthreads();

    const int wid  = t >> 6;
    const int lane = t & 63;
    const int col  = lane & 15;
    const int kg   = (lane >> 4) * 8;

    const int rowA = blockIdx.x * 64 + wid * 16 + col;   // A-frag row
    const size_t xbase = (size_t)min(rowA, N - 1) * K;

    f32x4 acc0 = {}, acc1 = {}, acc2 = {}, acc3 = {};

#pragma unroll
    for (int ks = 0; ks < K; ks += 32) {
        float4 xa = *(const float4*)&X[xbase + ks + kg];
        float4 xb = *(const float4*)&X[xbase + ks + kg + 4];
        const float xs[8] = {xa.x, xa.y, xa.z, xa.w, xb.x, xb.y, xb.z, xb.w};
        f16x8 ahi, alo;
#pragma unroll
        for (int j = 0; j < 8; ++j) {
            const _Float16 h = (_Float16)xs[j];
            ahi[j] = h;
            alo[j] = (_Float16)(xs[j] - (float)h);
        }
#pragma unroll
        for (int tile = 0; tile < 4; ++tile) {
            const f16x8 bhi = *(const f16x8*)&Wt[0][col + 16 * tile][ks + kg];
            const f16x8 blo = *(const f16x8*)&Wt[1][col + 16 * tile][ks + kg];
            f32x4* acc = (tile == 0) ? &acc0 : (tile == 1) ? &acc1
                       : (tile == 2) ? &acc2 : &acc3;
            *acc = __builtin_amdgcn_mfma_f32_16x16x32_f16(ahi, bhi, *acc, 0, 0, 0);
            *acc = __builtin_amdgcn_mfma_f32_16x16x32_f16(alo, bhi, *acc, 0, 0, 0);
            *acc = __builtin_amdgcn_mfma_f32_16x16x32_f16(ahi, blo, *acc, 0, 0, 0);
        }
    }

    // D layout: col = lane&15, row = (lane>>4)*4 + reg   [m89-verified]
    const int rbase = blockIdx.x * 64 + wid * 16 + (lane >> 4) * 4;
#pragma unroll
    for (int r = 0; r < 4; ++r) {
        const int rr = rbase + r;
        if (rr < N) {
            const float sc = rsqrtf((float)max(cnt_out[rr], 1));
            __half* yp = &Y[(size_t)rr * 64 + col];
            yp[0]  = __float2half_rn(acc0[r] * sc);
            yp[16] = __float2half_rn(acc1[r] * sc);
            yp[32] = __float2half_rn(acc2[r] * sc);
            yp[48] = __float2half_rn(acc3[r] * sc);
        }
    }
}

// FUSED layer-1 aggregate + layer-2 GEMM. Block = 16 nodes, 256 threads.
// Phase 1 (16 lanes/node, batch-12 clamped gathers): h = relu(agg*rs_in+b1),
// split hi/lo fp16 into LDS (hidden never touches HBM).
// Phase 2: wave w computes output col-tile 16w..16w+15 for all 16 nodes via
// mfma_f32_16x16x32_f16 (3-term hi/lo, fp32 acc), scaled by rs_out -> Y2.
// No early returns (clamped node ids) so barriers stay uniform.
__global__ __launch_bounds__(256)
void agg_gemm_kernel(const __half* __restrict__ Y,
                     const int* __restrict__ row_ptr,
                     const int* __restrict__ csr_src,
                     const int* __restrict__ cnt_in,
                     const int* __restrict__ cnt_out,
                     const float* __restrict__ b1,
                     const float* __restrict__ W2,
                     __half* __restrict__ Y2, int N) {
    __shared__ _Float16 Wt[2][64][72];     // [hi/lo][col][k], 72 = 64+8 pad
    __shared__ _Float16 Hh[16][72];
    __shared__ _Float16 Hl[16][72];
    const int t = threadIdx.x;

    // stage W2 hi/lo (reads L2-hot after first blocks)
    for (int i = t; i < 64 * 64; i += 256) {
        const int k = i >> 6, j = i & 63;
        const float w = W2[i];
        const _Float16 hi = (_Float16)w;
        Wt[0][j][k] = hi;
        Wt[1][j][k] = (_Float16)(w - (float)hi);
    }

    // ---- phase 1: aggregate (identical structure to aggregate_kernel) ----
    const int nl = t >> 4;                 // local node 0..15
    const int fq = t & 15;                 // features 4*fq .. 4*fq+3
    const int n  = blockIdx.x * 16 + nl;
    const int nc = min(n, N - 1);

    const int start = row_ptr[nc];
    const int end   = row_ptr[nc + 1];
    const int last  = end - 1;

    float4 acc = {0.f, 0.f, 0.f, 0.f};
    for (int e = start; e < end; e += 12) {
        int idx[12];
#pragma unroll
        for (int j = 0; j < 12; ++j) idx[j] = csr_src[min(e + j, last)];
        uint2 v[12];
#pragma unroll
        for (int j = 0; j < 12; ++j)
            v[j] = *((const uint2*)(Y + ((size_t)idx[j] << 6)) + fq);
#pragma unroll
        for (int j = 0; j < 12; ++j) {
            if (e + j < end) {
                float2 a = __half22float2(*(const __half2*)&v[j].x);
                float2 b = __half22float2(*(const __half2*)&v[j].y);
                acc.x += a.x; acc.y += a.y; acc.z += b.x; acc.w += b.y;
            }
        }
    }

    {
        const float sc = rsqrtf((float)max(cnt_in[nc], 1));
        const float4 bb = *(const float4*)&b1[4 * fq];
        float hv[4];
        hv[0] = fmaxf(acc.x * sc + bb.x, 0.f);
        hv[1] = fmaxf(acc.y * sc + bb.y, 0.f);
        hv[2] = fmaxf(acc.z * sc + bb.z, 0.f);
        hv[3] = fmaxf(acc.w * sc + bb.w, 0.f);
#pragma unroll
        for (int q = 0; q < 4; ++q) {
            const _Float16 hi = (_Float16)hv[q];
            Hh[nl][4 * fq + q] = hi;
            Hl[nl][4 * fq + q] = (_Float16)(hv[q] - (float)hi);
        }
    }
    __syncthreads();

    // ---- phase 2: 16x64 @ 64x64 MFMA, wave w -> col tile w ----
    const int wid  = t >> 6;
    const int lane = t & 63;
    const int col  = lane & 15;            // A row (node) AND B col-in-tile
    const int kg   = (lane >> 4) * 8;

    f32x4 acc2 = {};
#pragma unroll
    for (int ks = 0; ks < 64; ks += 32) {
        const f16x8 ahi = *(const f16x8*)&Hh[col][ks + kg];
        const f16x8 alo = *(const f16x8*)&Hl[col][ks + kg];
        const f16x8 bhi = *(const f16x8*)&Wt[0][16 * wid + col][ks + kg];
        const f16x8 blo = *(const f16x8*)&Wt[1][16 * wid + col][ks + kg];
        acc2 = __builtin_amdgcn_mfma_f32_16x16x32_f16(ahi, bhi, acc2, 0, 0, 0);
        acc2 = __builtin_amdgcn_mfma_f32_16x16x32_f16(alo, bhi, acc2, 0, 0, 0);
        acc2 = __builtin_amdgcn_mfma_f32_16x16x32_f16(ahi, blo, acc2, 0, 0, 0);
    }

    // D layout: col = lane&15, row = (lane>>4)*4 + reg
    const int rloc = (lane >> 4) * 4;
#pragma unroll
    for (int r = 0; r < 4; ++r) {
        const int rr = blockIdx.x * 16 + rloc + r;
        if (rr < N) {
            const float s2 = rsqrtf((float)max(cnt_out[rr], 1));
            Y2[(size_t)rr * 64 + 16 * wid + col] = __float2half_rn(acc2[r] * s2);
        }
    }
}

// out[n][f] = (sum_{in-edges} Y[src][f]) * rsqrt(max(cnt_in[n],1)) + bias[f]
// 16 lanes per node (4 nodes/wave); lane = 2 half2 feature pairs (8B gather).
template <bool RELU>
__global__ __launch_bounds__(256)
void aggregate_kernel(const __half* __restrict__ Y,
                      const int* __restrict__ row_ptr,
                      const int* __restrict__ csr_src,
                      const int* __restrict__ cnt_in,
                      const float* __restrict__ bias,
                      float* __restrict__ out, int N) {
    const int n = blockIdx.x * 16 + (threadIdx.x >> 4);
    if (n >= N) return;
    const int fq = threadIdx.x & 15;          // features 4*fq .. 4*fq+3

    const int start = row_ptr[n];
    const int end   = row_ptr[n + 1];
    const int last  = end - 1;

    float4 acc = {0.f, 0.f, 0.f, 0.f};
    for (int e = start; e < end; e += 12) {
        int idx[12];
#pragma unroll
        for (int j = 0; j < 12; ++j) idx[j] = csr_src[min(e + j, last)];
        uint2 v[12];
#pragma unroll
        for (int j = 0; j < 12; ++j)
            v[j] = *((const uint2*)(Y + ((size_t)idx[j] << 6)) + fq);
#pragma unroll
        for (int j = 0; j < 12; ++j) {
            if (e + j < end) {
                float2 a = __half22float2(*(const __half2*)&v[j].x);
                float2 b = __half22float2(*(const __half2*)&v[j].y);
                acc.x += a.x; acc.y += a.y; acc.z += b.x; acc.w += b.y;
            }
        }
    }

    const float sc = rsqrtf((float)max(cnt_in[n], 1));
    const float4 bb = *(const float4*)&bias[4 * fq];
    float4 o;
    o.x = acc.x * sc + bb.x;
    o.y = acc.y * sc + bb.y;
    o.z = acc.z * sc + bb.z;
    o.w = acc.w * sc + bb.w;
    if (RELU) {
        o.x = fmaxf(o.x, 0.f); o.y = fmaxf(o.y, 0.f);
        o.z = fmaxf(o.z, 0.f); o.w = fmaxf(o.w, 0.f);
    }
    *(float4*)&out[((size_t)n << 6) + 4 * fq] = o;
}

extern "C" void kernel_launch(void* const* d_in, const int* in_sizes, int n_in,
                              void* d_out, int out_size, void* d_ws, size_t ws_size,
                              hipStream_t stream) {
    const float* x   = (const float*)d_in[0];
    const int*   src = (const int*)d_in[1];
    const int*   dst = (const int*)d_in[2];
    const float* W1  = (const float*)d_in[3];
    const float* b1  = (const float*)d_in[4];
    const float* W2  = (const float*)d_in[5];
    const float* b2  = (const float*)d_in[6];
    float* out = (float*)d_out;

    const int N = in_sizes[0] / 128;   // 100000
    const int E = in_sizes[1];         // 1600000

    const int nbk = (N + BKT_W - 1) >> BKT_SHIFT;          // 391 buckets

    // Workspace (~45 MB of ~268 MB). d_out written only by the final agg.
    char* ws = (char*)d_ws;
    size_t off = 0;
    __half* Y       = (__half*)(ws + off); off = align256(off + (size_t)N * 64 * sizeof(__half));
    __half* Y2      = (__half*)(ws + off); off = align256(off + (size_t)N * 64 * sizeof(__half));
    int* csr_src    = (int*)(ws + off);    off = align256(off + (size_t)E * sizeof(int));
    int* ebuf       = (int*)(ws + off);    off = align256(off + (size_t)nbk * CAP * sizeof(int));
    unsigned char* sbuf = (unsigned char*)(ws + off); off = align256(off + (size_t)nbk * CAP);
    int* gcnt       = (int*)(ws + off);    off = align256(off + (size_t)2 * nbk * sizeof(int));
    int* gcnt_d     = gcnt;
    int* gcnt_s     = gcnt + nbk;
    int* cnt_out    = (int*)(ws + off);    off = align256(off + (size_t)N * sizeof(int));
    int* cnt_in     = (int*)(ws + off);    off = align256(off + (size_t)N * sizeof(int));
    int* row_ptr    = (int*)(ws + off);    off = align256(off + (size_t)(N + 1) * sizeof(int));

    const int pslice = (E + SC_BLOCKS - 1) / SC_BLOCKS;

    // Single-pass bucket partition (region counters zeroed first, one fill)
    hipMemsetAsync(gcnt, 0, (size_t)2 * nbk * sizeof(int), stream);
    scatter_atomic_kernel<<<SC_BLOCKS, SC_THREADS, 0, stream>>>(
        src, dst, gcnt_d, gcnt_s, ebuf, sbuf, nbk, E, pslice);
    bucket_csr_kernel<<<nbk, 256, 0, stream>>>(ebuf, sbuf, gcnt_d, gcnt_s, csr_src,
                                               cnt_in, cnt_out, row_ptr, nbk, N, E);

    const int gemm_blocks = (N + 63) / 64;
    const int agg_blocks  = (N + 15) / 16;

    // Layer 1 GEMM: Y = fp16[(X @ W1) * rs_out]
    gemm_scale_kernel<128><<<gemm_blocks, 256, 0, stream>>>(x, W1, cnt_out, Y, N);
    // Fused: agg1 (+b1, relu) -> hidden in LDS -> @W2 * rs_out -> Y2 fp16
    agg_gemm_kernel<<<agg_blocks, 256, 0, stream>>>(Y, row_ptr, csr_src,
                                                    cnt_in, cnt_out, b1, W2, Y2, N);
    // Layer 2 aggregate: out = agg(Y2) * rs_in + b2
    aggregate_kernel<false><<<agg_blocks, 256, 0, stream>>>(Y2, row_ptr, csr_src,
                                                            cnt_in, b2, out, N);
}